// Round 17
// baseline (192.789 us; speedup 1.0000x reference)
//
#include <hip/hip_runtime.h>
#include <hip/hip_bf16.h>
#include <cmath>

#define NB 8
#define NC 256
#define NHH 4
#define DD 64
#define LL 4096
#define NQ 64
#define NKB 64
#define BLK 64
#define TT 6
#define PAD 72  // f16 row stride (144B = 9*16B): 16B-aligned b128 ops

typedef _Float16 f16;
typedef _Float16 half8 __attribute__((ext_vector_type(8)));
typedef float f32x4 __attribute__((ext_vector_type(4)));
typedef unsigned int uint4v __attribute__((ext_vector_type(4)));
typedef unsigned long long ull;

#define INV2048 4.8828125e-4f

union H4 { f16 h[4]; ull u; };
union H2 { f16 h[2]; unsigned int u; };

#define MFMA16(A, B, C) __builtin_amdgcn_mfma_f32_16x16x32_f16(A, B, C, 0, 0, 0)

// ---------------- qb/kb: project block means (exact f32 topk path) ----------
__global__ void qbkb_kernel(const float* __restrict__ w, const float* __restrict__ xb,
                            float* __restrict__ qb, float* __restrict__ kb) {
  int id = blockIdx.x;
  int h = id % NHH; id /= NHH;
  int n = id % NQ;  int b = id / NQ;
  int t = threadIdx.x;
  int d = t & 63;
  int part = t >> 6;
  const float* wrow = w + (size_t)(part * NC + h * DD + d) * NC;
  const float* xcol = xb + (size_t)b * NC * NQ + n;
  float acc = 0.f;
#pragma unroll 4
  for (int c = 0; c < NC; ++c) acc += wrow[c] * xcol[(size_t)c * NQ];
  float* dst = (part == 0) ? qb : kb;
  dst[(((size_t)b * NHH + h) * NQ + n) * DD + d] = acc;
}

// ---------------- topk ----------------
__global__ void topk_kernel(const float* __restrict__ qb, const float* __restrict__ kb,
                            int* __restrict__ lut) {
  __shared__ float kbs[NKB][DD + 1];
  int id = blockIdx.x;
  int n = id % NQ;
  int bh = id / NQ;
  int m = threadIdx.x;
  const float* kbp = kb + (size_t)bh * NKB * DD;
  for (int i = threadIdx.x; i < NKB * DD; i += 64) kbs[i >> 6][i & 63] = kbp[i];
  __syncthreads();
  const float* qrow = qb + ((size_t)bh * NQ + n) * DD;
  float s = 0.f;
#pragma unroll 8
  for (int d2 = 0; d2 < DD; ++d2) s += qrow[d2] * kbs[m][d2];
  for (int t = 0; t < TT; ++t) {
    float v = s; int i = m;
#pragma unroll
    for (int off = 1; off < 64; off <<= 1) {
      float ov = __shfl_xor(v, off);
      int oi = __shfl_xor(i, off);
      if (ov > v || (ov == v && oi < i)) { v = ov; i = oi; }
    }
    if (m == 0) lut[(size_t)id * TT + t] = i;
    if (m == i) s = -INFINITY;
  }
}

// ---------------- merged weight split ----------------
__global__ void wsplit_kernel(const float* __restrict__ wq, const float* __restrict__ wo,
                              const float* __restrict__ plw,
                              f16* __restrict__ wqh,
                              f16* __restrict__ woh, f16* __restrict__ wol,
                              f16* __restrict__ plwh, f16* __restrict__ plwl) {
  int blk = blockIdx.x;
  if (blk < 192) {
    int i = (blk * 256 + threadIdx.x) * 4;
    float4 v = *(const float4*)(wq + i);
    H4 hh;
    hh.h[0] = (f16)v.x; hh.h[1] = (f16)v.y; hh.h[2] = (f16)v.z; hh.h[3] = (f16)v.w;
    *(ull*)(wqh + i) = hh.u;
    return;
  }
  const float* src; f16* dh; f16* dl; int n;
  if (blk < 256) { src = wo;  dh = woh;  dl = wol;  n = NC * NC; blk -= 192; }
  else           { src = plw; dh = plwh; dl = plwl; n = DD * DD; blk -= 256; }
  int i = (blk * 256 + threadIdx.x) * 4;
  if (i >= n) return;
  float4 v = *(const float4*)(src + i);
  H4 hh, ll;
  hh.h[0] = (f16)v.x; ll.h[0] = (f16)((v.x - (float)hh.h[0]) * 2048.f);
  hh.h[1] = (f16)v.y; ll.h[1] = (f16)((v.y - (float)hh.h[1]) * 2048.f);
  hh.h[2] = (f16)v.z; ll.h[2] = (f16)((v.z - (float)hh.h[2]) * 2048.f);
  hh.h[3] = (f16)v.w; ll.h[3] = (f16)((v.w - (float)hh.h[3]) * 2048.f);
  *(ull*)(dh + i) = hh.u;
  *(ull*)(dl + i) = ll.u;
}

// ---------------- x transpose + f16 + fused block means ----------------
__global__ __launch_bounds__(256) void xsplit_kernel(const float* __restrict__ x,
                                                     f16* __restrict__ xh,
                                                     float* __restrict__ xb) {
  __shared__ float T[64][65];
  int l0 = blockIdx.x * 64, c0 = blockIdx.y * 64, b = blockIdx.z;
  int tid = threadIdx.x;
  for (int it = 0; it < 16; ++it) {
    int idx = it * 256 + tid; int c = idx >> 6, l = idx & 63;
    T[c][l] = x[((size_t)b * NC + c0 + c) * LL + l0 + l];
  }
  __syncthreads();
  {  // fused xb: 4 lanes per row, 16-elem partials + 2 shfls
    int c = tid >> 2, qq = tid & 3;
    float s = 0.f;
#pragma unroll
    for (int l = 0; l < 16; ++l) s += T[c][qq * 16 + l];
    s += __shfl_xor(s, 1);
    s += __shfl_xor(s, 2);
    if (qq == 0) xb[((size_t)b * NC + c0 + c) * NQ + blockIdx.x] = s * (1.f / 64.f);
  }
  for (int it = 0; it < 4; ++it) {
    int idx = it * 256 + tid; int l = idx >> 4, cq = idx & 15;
    H4 hh;
    hh.h[0] = (f16)T[cq * 4 + 0][l];
    hh.h[1] = (f16)T[cq * 4 + 1][l];
    hh.h[2] = (f16)T[cq * 4 + 2][l];
    hh.h[3] = (f16)T[cq * 4 + 3][l];
    *(ull*)(xh + ((size_t)b * LL + l0 + l) * NC + c0 + cq * 4) = hh.u;
  }
}

// ---------------- q GEMM: single-MFMA, hi-only ----------------
__global__ __launch_bounds__(256, 8) void q_mfma(
    const f16* __restrict__ xh,
    const f16* __restrict__ wh,
    f16* __restrict__ qh) {
  __shared__ f16 XH[BLK][PAD];
  int L = blockIdx.x;
  int b = L & 7;            // xcd-pinned batch
  int t = L >> 3;           // 0..255
  int l0 = (t >> 2) * 64;
  int h = t & 3;
  int tid = threadIdx.x;
  int w = tid >> 6, lane = tid & 63, c16 = lane & 15, g = lane >> 4;
  f32x4 acc[4];
#pragma unroll
  for (int j = 0; j < 4; ++j) acc[j] = (f32x4){0.f,0.f,0.f,0.f};
  size_t wbase = (size_t)(h * DD + w * 16 + c16) * NC;
  for (int c0 = 0; c0 < NC; c0 += 64) {
    __syncthreads();
#pragma unroll
    for (int it = 0; it < 2; ++it) {
      int idx = it * 256 + tid; int pos = idx >> 3, dp8 = idx & 7;
      size_t gsrc = ((size_t)b * LL + l0 + pos) * NC + c0 + dp8 * 8;
      *(uint4v*)&XH[pos][dp8 * 8] = *(const uint4v*)(xh + gsrc);
    }
    __syncthreads();
#pragma unroll
    for (int ks = 0; ks < 2; ++ks) {
      half8 awh = *(const half8*)(wh + wbase + c0 + ks * 32 + g * 8);
#pragma unroll
      for (int j = 0; j < 4; ++j) {
        half8 bxh = *(const half8*)&XH[j * 16 + c16][ks * 32 + g * 8];
        acc[j] = MFMA16(awh, bxh, acc[j]);
      }
    }
  }
#pragma unroll
  for (int j = 0; j < 4; ++j) {
    H4 hh;
#pragma unroll
    for (int r = 0; r < 4; ++r) hh.h[r] = (f16)acc[j][r];
    size_t off = (((size_t)b * NHH + h) * LL + l0 + j * 16 + c16) * DD + w * 16 + g * 4;
    *(ull*)(qh + off) = hh.u;
  }
}

// ---------------- k+v GEMM with FUSED kvb (tile == key block) --------------
__global__ __launch_bounds__(256, 8) void kv_mfma(
    const f16* __restrict__ xh,
    const f16* __restrict__ wh,
    f16* __restrict__ kh, f16* __restrict__ vT,
    f16* __restrict__ kvbT, float* __restrict__ ksum) {
  __shared__ f16 XH[BLK][PAD];   // GEMM staging -> ck tile [l][d]
  __shared__ f16 VS[BLK][PAD];   // v tile [l][e]
  int L = blockIdx.x;
  int b = L & 7;
  int t = L >> 3;           // 0..255
  int l0 = (t >> 2) * 64;
  int h = t & 3;
  int m = l0 >> 6;          // key block index
  int tid = threadIdx.x;
  int w = tid >> 6, lane = tid & 63, c16 = lane & 15, g = lane >> 4;
  f32x4 acck[4], accv[4];
#pragma unroll
  for (int j = 0; j < 4; ++j) { acck[j] = (f32x4){0.f,0.f,0.f,0.f}; accv[j] = (f32x4){0.f,0.f,0.f,0.f}; }
  size_t wkbase = (size_t)(NC + h * DD + w * 16 + c16) * NC;
  size_t wvbase = (size_t)(2 * NC + h * DD + w * 16 + c16) * NC;
  for (int c0 = 0; c0 < NC; c0 += 64) {
    __syncthreads();
#pragma unroll
    for (int it = 0; it < 2; ++it) {
      int idx = it * 256 + tid; int pos = idx >> 3, dp8 = idx & 7;
      size_t gsrc = ((size_t)b * LL + l0 + pos) * NC + c0 + dp8 * 8;
      *(uint4v*)&XH[pos][dp8 * 8] = *(const uint4v*)(xh + gsrc);
    }
    __syncthreads();
#pragma unroll
    for (int ks = 0; ks < 2; ++ks) {
      half8 awk = *(const half8*)(wh + wkbase + c0 + ks * 32 + g * 8);
      half8 awv = *(const half8*)(wh + wvbase + c0 + ks * 32 + g * 8);
#pragma unroll
      for (int j = 0; j < 4; ++j) {
        half8 bxh = *(const half8*)&XH[j * 16 + c16][ks * 32 + g * 8];
        acck[j] = MFMA16(awk, bxh, acck[j]);
        accv[j] = MFMA16(awv, bxh, accv[j]);
      }
    }
  }
  int bh = b * NHH + h;
  // write kh (registers only)
#pragma unroll
  for (int j = 0; j < 4; ++j) {
    H4 hk;
#pragma unroll
    for (int r = 0; r < 4; ++r) hk.h[r] = (f16)acck[j][r];
    size_t off = ((size_t)bh * LL + l0 + j * 16 + c16) * DD + w * 16 + g * 4;
    *(ull*)(kh + off) = hk.u;
  }
  __syncthreads();  // all GEMM reads of XH done
  // stage k -> XH[l][d], v -> VS[l][e]
#pragma unroll
  for (int j = 0; j < 4; ++j)
#pragma unroll
    for (int r = 0; r < 4; ++r) {
      XH[j * 16 + c16][w * 16 + g * 4 + r] = (f16)acck[j][r];
      VS[j * 16 + c16][w * 16 + g * 4 + r] = (f16)accv[j][r];
    }
  __syncthreads();
  // emit vT[bh][e][l0+..] from VS
#pragma unroll
  for (int it = 0; it < 4; ++it) {
    int idx = it * 256 + tid; int d = idx >> 4, p4 = (idx & 15) * 4;
    H4 hh;
    hh.h[0] = VS[p4 + 0][d]; hh.h[1] = VS[p4 + 1][d];
    hh.h[2] = VS[p4 + 2][d]; hh.h[3] = VS[p4 + 3][d];
    *(ull*)(vT + ((size_t)bh * DD + d) * LL + l0 + p4) = hh.u;
  }
  // c_k softmax over d, in place in XH (4 threads/row, 16 cols each)
  {
    int r = tid >> 2, p = tid & 3;
    float v[16];
    float mx = -INFINITY;
#pragma unroll
    for (int c = 0; c < 16; ++c) { v[c] = (float)XH[r][p * 16 + c]; mx = fmaxf(mx, v[c]); }
    mx = fmaxf(mx, __shfl_xor(mx, 1));
    mx = fmaxf(mx, __shfl_xor(mx, 2));
    float sum = 0.f;
#pragma unroll
    for (int c = 0; c < 16; ++c) { v[c] = __expf(v[c] - mx); sum += v[c]; }
    sum += __shfl_xor(sum, 1);
    sum += __shfl_xor(sum, 2);
    float inv = 1.0f / sum;
#pragma unroll
    for (int c = 0; c < 16; ++c) XH[r][p * 16 + c] = (f16)(v[c] * inv);
  }
  __syncthreads();
  // ksum[d] = sum_l ck[l][d]
  if (tid < DD) {
    float s = 0.f;
#pragma unroll 8
    for (int j = 0; j < BLK; ++j) s += (float)XH[j][tid];
    ksum[((size_t)bh * NKB + m) * DD + tid] = s;
  }
  // kvbT[e][d] = sum_l v[l][e] * ck[l][d]
  int tx = tid & 15, ty = tid >> 4;
  float acc[4][4] = {};
#pragma unroll 4
  for (int j = 0; j < BLK; ++j) {
    H4 va = *(H4*)&VS[j][ty * 4];
    H4 ca = *(H4*)&XH[j][tx * 4];
    float a[4], bb[4];
#pragma unroll
    for (int i = 0; i < 4; ++i) { a[i] = (float)va.h[i]; bb[i] = (float)ca.h[i]; }
#pragma unroll
    for (int i = 0; i < 4; ++i)
#pragma unroll
      for (int jj = 0; jj < 4; ++jj) acc[i][jj] += a[i] * bb[jj];
  }
  f16* dst = kvbT + ((size_t)bh * NKB + m) * DD * DD;
#pragma unroll
  for (int i = 0; i < 4; ++i) {
    H4 hh;
#pragma unroll
    for (int jj = 0; jj < 4; ++jj) hh.h[jj] = (f16)acc[i][jj];
    *(ull*)(dst + (size_t)(ty * 4 + i) * DD + tx * 4) = hh.u;
  }
}

// ---------------- totals (parallelized: 512 blocks) ----------------
__global__ void totals_kernel(const f16* __restrict__ kvbT, const float* __restrict__ ksum,
                              float* __restrict__ kvtot, float* __restrict__ kstot) {
  int bi = blockIdx.x;
  int bh = bi >> 4, s = bi & 15;
  int tid = threadIdx.x;
  int i = s * 256 + tid;
  float acc = 0.f;
  const f16* src = kvbT + (size_t)bh * NKB * DD * DD + i;
  for (int m2 = 0; m2 < NKB; ++m2) acc += (float)src[(size_t)m2 * DD * DD];
  kvtot[(size_t)bh * DD * DD + i] = acc;
  if (s == 0 && tid < DD) {
    float ss = 0.f;
    for (int m2 = 0; m2 < NKB; ++m2) ss += ksum[((size_t)bh * NKB + m2) * DD + tid];
    kstot[(size_t)bh * DD + tid] = ss;
  }
}

// ---------------- fused attention ----------------
__global__ __launch_bounds__(256) void attn_mfma(
    const f16* __restrict__ qh_g,
    const f16* __restrict__ kh_g, const f16* __restrict__ vT_g,
    const f16* __restrict__ kvbT, const float* __restrict__ ksum,
    const float* __restrict__ kvtot, const float* __restrict__ kstot,
    const int* __restrict__ lut,
    const f16* __restrict__ plwh, const f16* __restrict__ plwl,
    const float* __restrict__ plb,
    f16* __restrict__ och) {
  __shared__ f16 KH[BLK][PAD], VH[BLK][PAD], PH[BLK][PAD];
  __shared__ float ksq[DD], dinv[BLK];
  int L = blockIdx.x;
  int rest = L >> 3;
  int bh = (L & 7) * 4 + (rest >> 6);  // xcd-pinned, bh sequential per xcd
  int n = rest & 63;
  int id = bh * NQ + n;
  int b = bh >> 2, h = bh & 3;
  int tid = threadIdx.x;
  int w = tid >> 6, lane = tid & 63, c16 = lane & 15, g = lane >> 4;
  int lu[TT];
#pragma unroll
  for (int t = 0; t < TT; ++t) lu[t] = lut[(size_t)id * TT + t];
  size_t qbase = ((size_t)bh * LL + (size_t)n * BLK + w * 16 + c16) * DD;
  half8 bqh[2];
#pragma unroll
  for (int ks = 0; ks < 2; ++ks) bqh[ks] = *(const half8*)(qh_g + qbase + ks * 32 + g * 8);
  f32x4 acco[4];
#pragma unroll
  for (int j = 0; j < 4; ++j) acco[j] = (f32x4){0.f,0.f,0.f,0.f};
  float l_run = 0.f;
  // async stage registers (T14): prefetch tile 0
  uint4v kreg[2], vreg[2];
  {
    int mb = lu[0];
#pragma unroll
    for (int it = 0; it < 2; ++it) {
      int idx = it * 256 + tid; int pos = idx >> 3, dp8 = idx & 7;
      kreg[it] = *(const uint4v*)(kh_g + ((size_t)bh * LL + (size_t)mb * BLK + pos) * DD + dp8 * 8);
      vreg[it] = *(const uint4v*)(vT_g + ((size_t)bh * DD + pos) * LL + (size_t)mb * BLK + dp8 * 8);
    }
  }
  for (int t = 0; t < TT; ++t) {
    __syncthreads();  // prior tile's readers done with LDS
#pragma unroll
    for (int it = 0; it < 2; ++it) {
      int idx = it * 256 + tid; int pos = idx >> 3, dp8 = idx & 7;
      *(uint4v*)&KH[pos][dp8 * 8] = kreg[it];
      *(uint4v*)&VH[pos][dp8 * 8] = vreg[it];
    }
    __syncthreads();
    if (t + 1 < TT) {  // issue next tile's loads; latency hides under compute
      int mb = lu[t + 1];
#pragma unroll
      for (int it = 0; it < 2; ++it) {
        int idx = it * 256 + tid; int pos = idx >> 3, dp8 = idx & 7;
        kreg[it] = *(const uint4v*)(kh_g + ((size_t)bh * LL + (size_t)mb * BLK + pos) * DD + dp8 * 8);
        vreg[it] = *(const uint4v*)(vT_g + ((size_t)bh * DD + pos) * LL + (size_t)mb * BLK + dp8 * 8);
      }
    }
    // QK^T single-f16; P = exp2(s*log2e/8 - 4*log2e), no max tracking
    float rs = 0.f;
#pragma unroll
    for (int i = 0; i < 4; ++i) {
      f32x4 acc = {0.f, 0.f, 0.f, 0.f};
#pragma unroll
      for (int ks = 0; ks < 2; ++ks) {
        half8 ah = *(const half8*)&KH[i * 16 + c16][ks * 32 + g * 8];
        acc = MFMA16(ah, bqh[ks], acc);
      }
      H4 pp;
#pragma unroll
      for (int r = 0; r < 4; ++r) {
        float p = exp2f(fmaf(acc[r], 0.18033688f, -5.7707801f));
        rs += p;
        pp.h[r] = (f16)p;
      }
      *(ull*)&PH[w * 16 + c16][i * 16 + g * 4] = pp.u;
    }
    rs += __shfl_xor(rs, 16);
    rs += __shfl_xor(rs, 32);
    l_run += rs;
#pragma unroll
    for (int ks = 0; ks < 2; ++ks) {
      half8 pb = *(const half8*)&PH[w * 16 + c16][ks * 32 + g * 8];
#pragma unroll
      for (int j = 0; j < 4; ++j) {
        half8 vhf = *(const half8*)&VH[j * 16 + c16][ks * 32 + g * 8];
        acco[j] = MFMA16(vhf, pb, acco[j]);
      }
    }
  }
  __syncthreads();  // last tile's LDS readers done before linear-path reuse
  float linv = 1.f / l_run;
#pragma unroll
  for (int j = 0; j < 4; ++j)
#pragma unroll
    for (int r = 0; r < 4; ++r) acco[j][r] *= linv;
  // ---- linear path ----
  if (tid < DD) {
    float s = kstot[(size_t)bh * DD + tid];
#pragma unroll
    for (int t2 = 0; t2 < TT; ++t2) s -= ksum[((size_t)bh * NKB + lu[t2]) * DD + tid];
    ksq[tid] = s;
  }
  int cr = tid >> 2, cp = tid & 3;
  float cq[16];
  {
    size_t qrow = ((size_t)bh * LL + (size_t)n * BLK + cr) * DD + cp * 16;
    half8 qa = *(const half8*)(qh_g + qrow), qa2 = *(const half8*)(qh_g + qrow + 8);
#pragma unroll
    for (int c = 0; c < 8; ++c) {
      cq[c] = (float)qa[c];
      cq[8 + c] = (float)qa2[c];
    }
    float mx2 = -INFINITY;
#pragma unroll
    for (int c = 0; c < 16; ++c) mx2 = fmaxf(mx2, cq[c]);
    mx2 = fmaxf(mx2, __shfl_xor(mx2, 1));
    mx2 = fmaxf(mx2, __shfl_xor(mx2, 2));
    float sum = 0.f;
#pragma unroll
    for (int c = 0; c < 16; ++c) { cq[c] = __expf(cq[c] - mx2); sum += cq[c]; }
    sum += __shfl_xor(sum, 1);
    sum += __shfl_xor(sum, 2);
    float inv = 1.f / sum;
#pragma unroll
    for (int c = 0; c < 16; ++c) cq[c] *= inv;
  }
#pragma unroll
  for (int c = 0; c < 8; ++c) {
    H2 hh, ll;
    hh.h[0] = (f16)cq[2 * c];     ll.h[0] = (f16)((cq[2 * c] - (float)hh.h[0]) * 2048.f);
    hh.h[1] = (f16)cq[2 * c + 1]; ll.h[1] = (f16)((cq[2 * c + 1] - (float)hh.h[1]) * 2048.f);
    *(unsigned int*)&VH[cr][cp * 16 + 2 * c] = hh.u;
    *(unsigned int*)&PH[cr][cp * 16 + 2 * c] = ll.u;
  }
  {
    // kvq^T gather: kvbT[m][e][dd] f16, lane = dd -> lane-contiguous reads
    const float* kvtp = kvtot + (size_t)bh * DD * DD;
    const f16* kvbp = kvbT + (size_t)bh * NKB * DD * DD;
    for (int it = 0; it < 16; ++it) {
      int idx = it * 256 + tid;
      int dd2 = idx & 63, e = idx >> 6;
      float s = kvtp[e * DD + dd2];
#pragma unroll
      for (int t2 = 0; t2 < TT; ++t2)
        s -= (float)kvbp[(size_t)lu[t2] * DD * DD + e * DD + dd2];
      KH[e][dd2] = (f16)s;
    }
  }
  __syncthreads();
  {
    float dpart = 0.f;
#pragma unroll
    for (int c = 0; c < 16; ++c) dpart += cq[c] * ksq[cp * 16 + c];
    dpart += __shfl_xor(dpart, 1);
    dpart += __shfl_xor(dpart, 2);
    if (cp == 0) dinv[cr] = 1.f / (dpart + 1e-6f);
  }
  f32x4 accn[4], accn2[4];
  {
    half8 cqh[2], cql[2];
#pragma unroll
    for (int ks = 0; ks < 2; ++ks) {
      cqh[ks] = *(const half8*)&VH[w * 16 + c16][ks * 32 + g * 8];
      cql[ks] = *(const half8*)&PH[w * 16 + c16][ks * 32 + g * 8];
    }
#pragma unroll
    for (int j = 0; j < 4; ++j) {
      f32x4 acc = {0.f, 0.f, 0.f, 0.f};
      f32x4 accc = {0.f, 0.f, 0.f, 0.f};
#pragma unroll
      for (int ks = 0; ks < 2; ++ks) {
        half8 ah = *(const half8*)&KH[j * 16 + c16][ks * 32 + g * 8];
        acc  = MFMA16(ah, cqh[ks], acc);
        accc = MFMA16(ah, cql[ks], accc);
      }
      accn[j] = acc; accn2[j] = accc;
    }
  }
  __syncthreads();
  float di = dinv[w * 16 + c16];
#pragma unroll
  for (int j = 0; j < 4; ++j) {
    float o0 = (accn[j][0] + accn2[j][0] * INV2048) * di;
    float o1 = (accn[j][1] + accn2[j][1] * INV2048) * di;
    float o2 = (accn[j][2] + accn2[j][2] * INV2048) * di;
    float o3 = (accn[j][3] + accn2[j][3] * INV2048) * di;
    H4 hh, ll;
    hh.h[0] = (f16)o0; ll.h[0] = (f16)((o0 - (float)hh.h[0]) * 2048.f);
    hh.h[1] = (f16)o1; ll.h[1] = (f16)((o1 - (float)hh.h[1]) * 2048.f);
    hh.h[2] = (f16)o2; ll.h[2] = (f16)((o2 - (float)hh.h[2]) * 2048.f);
    hh.h[3] = (f16)o3; ll.h[3] = (f16)((o3 - (float)hh.h[3]) * 2048.f);
    *(ull*)&PH[w * 16 + c16][j * 16 + g * 4] = hh.u;
    *(ull*)&KH[w * 16 + c16][j * 16 + g * 4] = ll.u;
  }
  f32x4 accf2[4];
#pragma unroll
  for (int j = 0; j < 4; ++j) accf2[j] = (f32x4){0.f,0.f,0.f,0.f};
#pragma unroll
  for (int ks = 0; ks < 2; ++ks) {
    half8 bolh = *(const half8*)&PH[w * 16 + c16][ks * 32 + g * 8];
    half8 boll = *(const half8*)&KH[w * 16 + c16][ks * 32 + g * 8];
#pragma unroll
    for (int j = 0; j < 4; ++j) {
      size_t pwoff = (size_t)(j * 16 + c16) * DD + ks * 32 + g * 8;
      half8 awh = *(const half8*)(plwh + pwoff);
      half8 awl = *(const half8*)(plwl + pwoff);
      acco[j]  = MFMA16(awh, bolh, acco[j]);
      accf2[j] = MFMA16(awh, boll, accf2[j]);
      accf2[j] = MFMA16(awl, bolh, accf2[j]);
    }
  }
  size_t obase = ((size_t)b * LL + (size_t)n * BLK + w * 16 + c16) * NC + h * DD;
#pragma unroll
  for (int j = 0; j < 4; ++j) {
    H4 hh;
#pragma unroll
    for (int r = 0; r < 4; ++r) {
      int e2 = j * 16 + g * 4 + r;
      hh.h[r] = (f16)(acco[j][r] + accf2[j][r] * INV2048 + plb[e2]);
    }
    *(ull*)(och + obase + j * 16 + g * 4) = hh.u;
  }
}

// ---------------- out projection: och staged ONCE (full K), 4 o-passes ------
__global__ __launch_bounds__(256) void out_mfma(
    const f16* __restrict__ och,
    const f16* __restrict__ wh, const f16* __restrict__ wl,
    float* __restrict__ out) {
  __shared__ f16 OH[BLK][NC + 8];
  int l0 = blockIdx.x * 64;
  int b = blockIdx.y;
  int tid = threadIdx.x;
  int w = tid >> 6, lane = tid & 63, c16 = lane & 15, g = lane >> 4;
  // stage och tile [64 l][256 c] once
#pragma unroll
  for (int it = 0; it < 8; ++it) {
    int idx = it * 256 + tid; int l = idx >> 5, c8 = idx & 31;
    *(uint4v*)&OH[l][c8 * 8] =
        *(const uint4v*)(och + ((size_t)b * LL + l0 + l) * NC + c8 * 8);
  }
  __syncthreads();
#pragma unroll 1
  for (int oq = 0; oq < 4; ++oq) {
    size_t wbase = (size_t)(oq * 64 + w * 16 + c16) * NC;
    f32x4 acc[4], acc2[4];
#pragma unroll
    for (int j = 0; j < 4; ++j) { acc[j] = (f32x4){0.f,0.f,0.f,0.f}; acc2[j] = (f32x4){0.f,0.f,0.f,0.f}; }
#pragma unroll
    for (int ks = 0; ks < 8; ++ks) {
      half8 awh = *(const half8*)(wh + wbase + ks * 32 + g * 8);
      half8 awl = *(const half8*)(wl + wbase + ks * 32 + g * 8);
#pragma unroll
      for (int j = 0; j < 4; ++j) {
        half8 bh = *(const half8*)&OH[j * 16 + c16][ks * 32 + g * 8];
        acc[j]  = MFMA16(awh, bh, acc[j]);
        acc2[j] = MFMA16(awl, bh, acc2[j]);
      }
    }
#pragma unroll
    for (int j = 0; j < 4; ++j)
#pragma unroll
      for (int r = 0; r < 4; ++r)
        out[((size_t)b * NC + oq * 64 + w * 16 + g * 4 + r) * LL + l0 + j * 16 + c16] =
            acc[j][r] + acc2[j][r] * INV2048;
  }
}

extern "C" void kernel_launch(void* const* d_in, const int* in_sizes, int n_in,
                              void* d_out, int out_size, void* d_ws, size_t ws_size,
                              hipStream_t stream) {
  (void)in_sizes; (void)n_in; (void)out_size; (void)ws_size;
  const float* x = (const float*)d_in[0];
  const float* qkv_w = (const float*)d_in[1];
  const float* out_w = (const float*)d_in[2];
  const float* plw = (const float*)d_in[3];
  const float* plb = (const float*)d_in[4];
  float* out = (float*)d_out;
  const size_t E = (size_t)NB * NHH * LL * DD;  // 8388608
  f16* fb = (f16*)d_ws;
  f16* qh = fb;
  f16* kh = qh + E;
  f16* vT = kh + E;
  f16* xTh = vT + E;
  // och aliases xTh (xTh consumed by q/kv_mfma before attn writes och)
  f16* och = xTh;
  f16* kvbT = xTh + E;
  float* fbase = (float*)(kvbT + E);
  float* ksum = fbase;
  float* kvtot = ksum + (size_t)NB * NHH * NKB * DD;
  float* kstot = kvtot + (size_t)NB * NHH * DD * DD;
  float* xb = kstot + (size_t)NB * NHH * DD;
  float* qb = xb + (size_t)NB * NC * NQ;
  float* kb = qb + (size_t)NB * NHH * NQ * DD;
  int* lut = (int*)(kb + (size_t)NB * NHH * NQ * DD);
  f16* wqh = (f16*)(lut + (size_t)NB * NHH * NQ * TT);
  f16* woh = wqh + (size_t)3 * NC * NC;
  f16* wol = woh + (size_t)NC * NC;
  f16* plwh = wol + (size_t)NC * NC;
  f16* plwl = plwh + (size_t)DD * DD;

  xsplit_kernel<<<dim3(LL / 64, NC / 64, NB), 256, 0, stream>>>(x, xTh, xb);
  qbkb_kernel<<<NB * NQ * NHH, 128, 0, stream>>>(qkv_w, xb, qb, kb);
  topk_kernel<<<NB * NHH * NQ, 64, 0, stream>>>(qb, kb, lut);
  wsplit_kernel<<<260, 256, 0, stream>>>(qkv_w, out_w, plw, wqh, woh, wol, plwh, plwl);
  q_mfma<<<LL / 64 * NHH * NB, 256, 0, stream>>>(xTh, wqh, qh);
  kv_mfma<<<LL / 64 * NHH * NB, 256, 0, stream>>>(xTh, wqh, kh, vT, kvbT, ksum);
  totals_kernel<<<NB * NHH * 16, 256, 0, stream>>>(kvbT, ksum, kvtot, kstot);
  attn_mfma<<<NB * NHH * NQ, 256, 0, stream>>>(qh, kh, vT, kvbT, ksum,
                                               kvtot, kstot, lut, plwh, plwl, plb,
                                               och);
  out_mfma<<<dim3(LL / 64, NB), 256, 0, stream>>>(och, woh, wol, out);
}

// Round 18
// 188.974 us; speedup vs baseline: 1.0202x; 1.0202x over previous
//
#include <hip/hip_runtime.h>
#include <hip/hip_bf16.h>
#include <cmath>

#define NB 8
#define NC 256
#define NHH 4
#define DD 64
#define LL 4096
#define NQ 64
#define NKB 64
#define BLK 64
#define TT 6
#define PAD 72  // f16 row stride (144B = 9*16B): 16B-aligned b128 ops

typedef _Float16 f16;
typedef _Float16 half8 __attribute__((ext_vector_type(8)));
typedef float f32x4 __attribute__((ext_vector_type(4)));
typedef unsigned int uint4v __attribute__((ext_vector_type(4)));
typedef unsigned long long ull;

#define INV2048 4.8828125e-4f

union H4 { f16 h[4]; ull u; };
union H2 { f16 h[2]; unsigned int u; };

#define MFMA16(A, B, C) __builtin_amdgcn_mfma_f32_16x16x32_f16(A, B, C, 0, 0, 0)

// ---------------- qb/kb: project block means (exact f32 topk path) ----------
__global__ void qbkb_kernel(const float* __restrict__ w, const float* __restrict__ xb,
                            float* __restrict__ qb, float* __restrict__ kb) {
  int id = blockIdx.x;
  int h = id % NHH; id /= NHH;
  int n = id % NQ;  int b = id / NQ;
  int t = threadIdx.x;
  int d = t & 63;
  int part = t >> 6;
  const float* wrow = w + (size_t)(part * NC + h * DD + d) * NC;
  const float* xcol = xb + (size_t)b * NC * NQ + n;
  float acc = 0.f;
#pragma unroll 4
  for (int c = 0; c < NC; ++c) acc += wrow[c] * xcol[(size_t)c * NQ];
  float* dst = (part == 0) ? qb : kb;
  dst[(((size_t)b * NHH + h) * NQ + n) * DD + d] = acc;
}

// ---------------- topk ----------------
__global__ void topk_kernel(const float* __restrict__ qb, const float* __restrict__ kb,
                            int* __restrict__ lut) {
  __shared__ float kbs[NKB][DD + 1];
  int id = blockIdx.x;
  int n = id % NQ;
  int bh = id / NQ;
  int m = threadIdx.x;
  const float* kbp = kb + (size_t)bh * NKB * DD;
  for (int i = threadIdx.x; i < NKB * DD; i += 64) kbs[i >> 6][i & 63] = kbp[i];
  __syncthreads();
  const float* qrow = qb + ((size_t)bh * NQ + n) * DD;
  float s = 0.f;
#pragma unroll 8
  for (int d2 = 0; d2 < DD; ++d2) s += qrow[d2] * kbs[m][d2];
  for (int t = 0; t < TT; ++t) {
    float v = s; int i = m;
#pragma unroll
    for (int off = 1; off < 64; off <<= 1) {
      float ov = __shfl_xor(v, off);
      int oi = __shfl_xor(i, off);
      if (ov > v || (ov == v && oi < i)) { v = ov; i = oi; }
    }
    if (m == 0) lut[(size_t)id * TT + t] = i;
    if (m == i) s = -INFINITY;
  }
}

// ---------------- merged weight split ----------------
__global__ void wsplit_kernel(const float* __restrict__ wq, const float* __restrict__ wo,
                              const float* __restrict__ plw,
                              f16* __restrict__ wqh,
                              f16* __restrict__ woh, f16* __restrict__ wol,
                              f16* __restrict__ plwh, f16* __restrict__ plwl) {
  int blk = blockIdx.x;
  if (blk < 192) {
    int i = (blk * 256 + threadIdx.x) * 4;
    float4 v = *(const float4*)(wq + i);
    H4 hh;
    hh.h[0] = (f16)v.x; hh.h[1] = (f16)v.y; hh.h[2] = (f16)v.z; hh.h[3] = (f16)v.w;
    *(ull*)(wqh + i) = hh.u;
    return;
  }
  const float* src; f16* dh; f16* dl; int n;
  if (blk < 256) { src = wo;  dh = woh;  dl = wol;  n = NC * NC; blk -= 192; }
  else           { src = plw; dh = plwh; dl = plwl; n = DD * DD; blk -= 256; }
  int i = (blk * 256 + threadIdx.x) * 4;
  if (i >= n) return;
  float4 v = *(const float4*)(src + i);
  H4 hh, ll;
  hh.h[0] = (f16)v.x; ll.h[0] = (f16)((v.x - (float)hh.h[0]) * 2048.f);
  hh.h[1] = (f16)v.y; ll.h[1] = (f16)((v.y - (float)hh.h[1]) * 2048.f);
  hh.h[2] = (f16)v.z; ll.h[2] = (f16)((v.z - (float)hh.h[2]) * 2048.f);
  hh.h[3] = (f16)v.w; ll.h[3] = (f16)((v.w - (float)hh.h[3]) * 2048.f);
  *(ull*)(dh + i) = hh.u;
  *(ull*)(dl + i) = ll.u;
}

// ---------------- x transpose + f16 + fused block means ----------------
__global__ __launch_bounds__(256) void xsplit_kernel(const float* __restrict__ x,
                                                     f16* __restrict__ xh,
                                                     float* __restrict__ xb) {
  __shared__ float T[64][65];
  int l0 = blockIdx.x * 64, c0 = blockIdx.y * 64, b = blockIdx.z;
  int tid = threadIdx.x;
  for (int it = 0; it < 16; ++it) {
    int idx = it * 256 + tid; int c = idx >> 6, l = idx & 63;
    T[c][l] = x[((size_t)b * NC + c0 + c) * LL + l0 + l];
  }
  __syncthreads();
  {  // fused xb: 4 lanes per row, 16-elem partials + 2 shfls
    int c = tid >> 2, qq = tid & 3;
    float s = 0.f;
#pragma unroll
    for (int l = 0; l < 16; ++l) s += T[c][qq * 16 + l];
    s += __shfl_xor(s, 1);
    s += __shfl_xor(s, 2);
    if (qq == 0) xb[((size_t)b * NC + c0 + c) * NQ + blockIdx.x] = s * (1.f / 64.f);
  }
  for (int it = 0; it < 4; ++it) {
    int idx = it * 256 + tid; int l = idx >> 4, cq = idx & 15;
    H4 hh;
    hh.h[0] = (f16)T[cq * 4 + 0][l];
    hh.h[1] = (f16)T[cq * 4 + 1][l];
    hh.h[2] = (f16)T[cq * 4 + 2][l];
    hh.h[3] = (f16)T[cq * 4 + 3][l];
    *(ull*)(xh + ((size_t)b * LL + l0 + l) * NC + c0 + cq * 4) = hh.u;
  }
}

// ---------------- q GEMM: single-MFMA, hi-only ----------------
__global__ __launch_bounds__(256, 8) void q_mfma(
    const f16* __restrict__ xh,
    const f16* __restrict__ wh,
    f16* __restrict__ qh) {
  __shared__ f16 XH[BLK][PAD];
  int L = blockIdx.x;
  int b = L & 7;            // xcd-pinned batch
  int t = L >> 3;           // 0..255
  int l0 = (t >> 2) * 64;
  int h = t & 3;
  int tid = threadIdx.x;
  int w = tid >> 6, lane = tid & 63, c16 = lane & 15, g = lane >> 4;
  f32x4 acc[4];
#pragma unroll
  for (int j = 0; j < 4; ++j) acc[j] = (f32x4){0.f,0.f,0.f,0.f};
  size_t wbase = (size_t)(h * DD + w * 16 + c16) * NC;
  for (int c0 = 0; c0 < NC; c0 += 64) {
    __syncthreads();
#pragma unroll
    for (int it = 0; it < 2; ++it) {
      int idx = it * 256 + tid; int pos = idx >> 3, dp8 = idx & 7;
      size_t gsrc = ((size_t)b * LL + l0 + pos) * NC + c0 + dp8 * 8;
      *(uint4v*)&XH[pos][dp8 * 8] = *(const uint4v*)(xh + gsrc);
    }
    __syncthreads();
#pragma unroll
    for (int ks = 0; ks < 2; ++ks) {
      half8 awh = *(const half8*)(wh + wbase + c0 + ks * 32 + g * 8);
#pragma unroll
      for (int j = 0; j < 4; ++j) {
        half8 bxh = *(const half8*)&XH[j * 16 + c16][ks * 32 + g * 8];
        acc[j] = MFMA16(awh, bxh, acc[j]);
      }
    }
  }
#pragma unroll
  for (int j = 0; j < 4; ++j) {
    H4 hh;
#pragma unroll
    for (int r = 0; r < 4; ++r) hh.h[r] = (f16)acc[j][r];
    size_t off = (((size_t)b * NHH + h) * LL + l0 + j * 16 + c16) * DD + w * 16 + g * 4;
    *(ull*)(qh + off) = hh.u;
  }
}

// ---------------- k+v GEMM with FUSED kvb (tile == key block) --------------
__global__ __launch_bounds__(256, 8) void kv_mfma(
    const f16* __restrict__ xh,
    const f16* __restrict__ wh,
    f16* __restrict__ kh, f16* __restrict__ vT,
    f16* __restrict__ kvbT, float* __restrict__ ksum) {
  __shared__ f16 XH[BLK][PAD];   // GEMM staging -> ck tile [l][d]
  __shared__ f16 VS[BLK][PAD];   // v tile [l][e]
  int L = blockIdx.x;
  int b = L & 7;
  int t = L >> 3;           // 0..255
  int l0 = (t >> 2) * 64;
  int h = t & 3;
  int m = l0 >> 6;          // key block index
  int tid = threadIdx.x;
  int w = tid >> 6, lane = tid & 63, c16 = lane & 15, g = lane >> 4;
  f32x4 acck[4], accv[4];
#pragma unroll
  for (int j = 0; j < 4; ++j) { acck[j] = (f32x4){0.f,0.f,0.f,0.f}; accv[j] = (f32x4){0.f,0.f,0.f,0.f}; }
  size_t wkbase = (size_t)(NC + h * DD + w * 16 + c16) * NC;
  size_t wvbase = (size_t)(2 * NC + h * DD + w * 16 + c16) * NC;
  for (int c0 = 0; c0 < NC; c0 += 64) {
    __syncthreads();
#pragma unroll
    for (int it = 0; it < 2; ++it) {
      int idx = it * 256 + tid; int pos = idx >> 3, dp8 = idx & 7;
      size_t gsrc = ((size_t)b * LL + l0 + pos) * NC + c0 + dp8 * 8;
      *(uint4v*)&XH[pos][dp8 * 8] = *(const uint4v*)(xh + gsrc);
    }
    __syncthreads();
#pragma unroll
    for (int ks = 0; ks < 2; ++ks) {
      half8 awk = *(const half8*)(wh + wkbase + c0 + ks * 32 + g * 8);
      half8 awv = *(const half8*)(wh + wvbase + c0 + ks * 32 + g * 8);
#pragma unroll
      for (int j = 0; j < 4; ++j) {
        half8 bxh = *(const half8*)&XH[j * 16 + c16][ks * 32 + g * 8];
        acck[j] = MFMA16(awk, bxh, acck[j]);
        accv[j] = MFMA16(awv, bxh, accv[j]);
      }
    }
  }
  int bh = b * NHH + h;
  // write kh (registers only)
#pragma unroll
  for (int j = 0; j < 4; ++j) {
    H4 hk;
#pragma unroll
    for (int r = 0; r < 4; ++r) hk.h[r] = (f16)acck[j][r];
    size_t off = ((size_t)bh * LL + l0 + j * 16 + c16) * DD + w * 16 + g * 4;
    *(ull*)(kh + off) = hk.u;
  }
  __syncthreads();  // all GEMM reads of XH done
  // stage k -> XH[l][d], v -> VS[l][e]
#pragma unroll
  for (int j = 0; j < 4; ++j)
#pragma unroll
    for (int r = 0; r < 4; ++r) {
      XH[j * 16 + c16][w * 16 + g * 4 + r] = (f16)acck[j][r];
      VS[j * 16 + c16][w * 16 + g * 4 + r] = (f16)accv[j][r];
    }
  __syncthreads();
  // emit vT[bh][e][l0+..] from VS
#pragma unroll
  for (int it = 0; it < 4; ++it) {
    int idx = it * 256 + tid; int d = idx >> 4, p4 = (idx & 15) * 4;
    H4 hh;
    hh.h[0] = VS[p4 + 0][d]; hh.h[1] = VS[p4 + 1][d];
    hh.h[2] = VS[p4 + 2][d]; hh.h[3] = VS[p4 + 3][d];
    *(ull*)(vT + ((size_t)bh * DD + d) * LL + l0 + p4) = hh.u;
  }
  // c_k softmax over d, in place in XH (4 threads/row, 16 cols each)
  {
    int r = tid >> 2, p = tid & 3;
    float v[16];
    float mx = -INFINITY;
#pragma unroll
    for (int c = 0; c < 16; ++c) { v[c] = (float)XH[r][p * 16 + c]; mx = fmaxf(mx, v[c]); }
    mx = fmaxf(mx, __shfl_xor(mx, 1));
    mx = fmaxf(mx, __shfl_xor(mx, 2));
    float sum = 0.f;
#pragma unroll
    for (int c = 0; c < 16; ++c) { v[c] = __expf(v[c] - mx); sum += v[c]; }
    sum += __shfl_xor(sum, 1);
    sum += __shfl_xor(sum, 2);
    float inv = 1.0f / sum;
#pragma unroll
    for (int c = 0; c < 16; ++c) XH[r][p * 16 + c] = (f16)(v[c] * inv);
  }
  __syncthreads();
  // ksum[d] = sum_l ck[l][d]
  if (tid < DD) {
    float s = 0.f;
#pragma unroll 8
    for (int j = 0; j < BLK; ++j) s += (float)XH[j][tid];
    ksum[((size_t)bh * NKB + m) * DD + tid] = s;
  }
  // kvbT[e][d] = sum_l v[l][e] * ck[l][d]
  int tx = tid & 15, ty = tid >> 4;
  float acc[4][4] = {};
#pragma unroll 4
  for (int j = 0; j < BLK; ++j) {
    H4 va = *(H4*)&VS[j][ty * 4];
    H4 ca = *(H4*)&XH[j][tx * 4];
    float a[4], bb[4];
#pragma unroll
    for (int i = 0; i < 4; ++i) { a[i] = (float)va.h[i]; bb[i] = (float)ca.h[i]; }
#pragma unroll
    for (int i = 0; i < 4; ++i)
#pragma unroll
      for (int jj = 0; jj < 4; ++jj) acc[i][jj] += a[i] * bb[jj];
  }
  f16* dst = kvbT + ((size_t)bh * NKB + m) * DD * DD;
#pragma unroll
  for (int i = 0; i < 4; ++i) {
    H4 hh;
#pragma unroll
    for (int jj = 0; jj < 4; ++jj) hh.h[jj] = (f16)acc[i][jj];
    *(ull*)(dst + (size_t)(ty * 4 + i) * DD + tx * 4) = hh.u;
  }
}

// ---------------- totals (parallelized: 512 blocks) ----------------
__global__ void totals_kernel(const f16* __restrict__ kvbT, const float* __restrict__ ksum,
                              float* __restrict__ kvtot, float* __restrict__ kstot) {
  int bi = blockIdx.x;
  int bh = bi >> 4, s = bi & 15;
  int tid = threadIdx.x;
  int i = s * 256 + tid;
  float acc = 0.f;
  const f16* src = kvbT + (size_t)bh * NKB * DD * DD + i;
  for (int m2 = 0; m2 < NKB; ++m2) acc += (float)src[(size_t)m2 * DD * DD];
  kvtot[(size_t)bh * DD * DD + i] = acc;
  if (s == 0 && tid < DD) {
    float ss = 0.f;
    for (int m2 = 0; m2 < NKB; ++m2) ss += ksum[((size_t)bh * NKB + m2) * DD + tid];
    kstot[(size_t)bh * DD + tid] = ss;
  }
}

// ---------------- fused attention ----------------
// cq used at f16 precision only (convexity-protected: num/den share weights).
__global__ __launch_bounds__(256) void attn_mfma(
    const f16* __restrict__ qh_g,
    const f16* __restrict__ kh_g, const f16* __restrict__ vT_g,
    const f16* __restrict__ kvbT, const float* __restrict__ ksum,
    const float* __restrict__ kvtot, const float* __restrict__ kstot,
    const int* __restrict__ lut,
    const f16* __restrict__ plwh, const f16* __restrict__ plwl,
    const float* __restrict__ plb,
    f16* __restrict__ och) {
  __shared__ f16 KH[BLK][PAD], VH[BLK][PAD], PH[BLK][PAD];
  __shared__ float ksq[DD], dinv[BLK];
  int L = blockIdx.x;
  int rest = L >> 3;
  int bh = (L & 7) * 4 + (rest >> 6);  // xcd-pinned, bh sequential per xcd
  int n = rest & 63;
  int id = bh * NQ + n;
  int b = bh >> 2, h = bh & 3;
  int tid = threadIdx.x;
  int w = tid >> 6, lane = tid & 63, c16 = lane & 15, g = lane >> 4;
  int lu[TT];
#pragma unroll
  for (int t = 0; t < TT; ++t) lu[t] = lut[(size_t)id * TT + t];
  size_t qbase = ((size_t)bh * LL + (size_t)n * BLK + w * 16 + c16) * DD;
  half8 bqh[2];
#pragma unroll
  for (int ks = 0; ks < 2; ++ks) bqh[ks] = *(const half8*)(qh_g + qbase + ks * 32 + g * 8);
  f32x4 acco[4];
#pragma unroll
  for (int j = 0; j < 4; ++j) acco[j] = (f32x4){0.f,0.f,0.f,0.f};
  float l_run = 0.f;
  // async stage registers (T14): prefetch tile 0
  uint4v kreg[2], vreg[2];
  {
    int mb = lu[0];
#pragma unroll
    for (int it = 0; it < 2; ++it) {
      int idx = it * 256 + tid; int pos = idx >> 3, dp8 = idx & 7;
      kreg[it] = *(const uint4v*)(kh_g + ((size_t)bh * LL + (size_t)mb * BLK + pos) * DD + dp8 * 8);
      vreg[it] = *(const uint4v*)(vT_g + ((size_t)bh * DD + pos) * LL + (size_t)mb * BLK + dp8 * 8);
    }
  }
  for (int t = 0; t < TT; ++t) {
    __syncthreads();  // prior tile's readers done with LDS
#pragma unroll
    for (int it = 0; it < 2; ++it) {
      int idx = it * 256 + tid; int pos = idx >> 3, dp8 = idx & 7;
      *(uint4v*)&KH[pos][dp8 * 8] = kreg[it];
      *(uint4v*)&VH[pos][dp8 * 8] = vreg[it];
    }
    __syncthreads();
    if (t + 1 < TT) {  // issue next tile's loads; latency hides under compute
      int mb = lu[t + 1];
#pragma unroll
      for (int it = 0; it < 2; ++it) {
        int idx = it * 256 + tid; int pos = idx >> 3, dp8 = idx & 7;
        kreg[it] = *(const uint4v*)(kh_g + ((size_t)bh * LL + (size_t)mb * BLK + pos) * DD + dp8 * 8);
        vreg[it] = *(const uint4v*)(vT_g + ((size_t)bh * DD + pos) * LL + (size_t)mb * BLK + dp8 * 8);
      }
    }
    // QK^T single-f16; P = exp(s/8 - 4), no max tracking
    float rs = 0.f;
#pragma unroll
    for (int i = 0; i < 4; ++i) {
      f32x4 acc = {0.f, 0.f, 0.f, 0.f};
#pragma unroll
      for (int ks = 0; ks < 2; ++ks) {
        half8 ah = *(const half8*)&KH[i * 16 + c16][ks * 32 + g * 8];
        acc = MFMA16(ah, bqh[ks], acc);
      }
      H4 pp;
#pragma unroll
      for (int r = 0; r < 4; ++r) {
        float p = __expf(acc[r] * 0.125f - 4.f);
        rs += p;
        pp.h[r] = (f16)p;
      }
      *(ull*)&PH[w * 16 + c16][i * 16 + g * 4] = pp.u;
    }
    rs += __shfl_xor(rs, 16);
    rs += __shfl_xor(rs, 32);
    l_run += rs;
#pragma unroll
    for (int ks = 0; ks < 2; ++ks) {
      half8 pb = *(const half8*)&PH[w * 16 + c16][ks * 32 + g * 8];
#pragma unroll
      for (int j = 0; j < 4; ++j) {
        half8 vhf = *(const half8*)&VH[j * 16 + c16][ks * 32 + g * 8];
        acco[j] = MFMA16(vhf, pb, acco[j]);
      }
    }
  }
  __syncthreads();  // last tile's LDS readers done before linear-path reuse
  float linv = 1.f / l_run;
#pragma unroll
  for (int j = 0; j < 4; ++j)
#pragma unroll
    for (int r = 0; r < 4; ++r) acco[j][r] *= linv;
  // ---- linear path ----
  if (tid < DD) {
    float s = kstot[(size_t)bh * DD + tid];
#pragma unroll
    for (int t2 = 0; t2 < TT; ++t2) s -= ksum[((size_t)bh * NKB + lu[t2]) * DD + tid];
    ksq[tid] = s;
  }
  int cr = tid >> 2, cp = tid & 3;
  float cq[16];
  {
    size_t qrow = ((size_t)bh * LL + (size_t)n * BLK + cr) * DD + cp * 16;
    half8 qa = *(const half8*)(qh_g + qrow), qa2 = *(const half8*)(qh_g + qrow + 8);
#pragma unroll
    for (int c = 0; c < 8; ++c) {
      cq[c] = (float)qa[c];
      cq[8 + c] = (float)qa2[c];
    }
    float mx2 = -INFINITY;
#pragma unroll
    for (int c = 0; c < 16; ++c) mx2 = fmaxf(mx2, cq[c]);
    mx2 = fmaxf(mx2, __shfl_xor(mx2, 1));
    mx2 = fmaxf(mx2, __shfl_xor(mx2, 2));
    float sum = 0.f;
#pragma unroll
    for (int c = 0; c < 16; ++c) { cq[c] = __expf(cq[c] - mx2); sum += cq[c]; }
    sum += __shfl_xor(sum, 1);
    sum += __shfl_xor(sum, 2);
    float inv = 1.f / sum;
#pragma unroll
    for (int c = 0; c < 16; ++c) cq[c] *= inv;
  }
#pragma unroll
  for (int c = 0; c < 8; ++c) {
    H2 hh;
    hh.h[0] = (f16)cq[2 * c];
    hh.h[1] = (f16)cq[2 * c + 1];
    *(unsigned int*)&VH[cr][cp * 16 + 2 * c] = hh.u;
  }
  {
    // kvq^T gather: kvbT[m][e][dd] f16, lane = dd -> lane-contiguous reads
    const float* kvtp = kvtot + (size_t)bh * DD * DD;
    const f16* kvbp = kvbT + (size_t)bh * NKB * DD * DD;
    for (int it = 0; it < 16; ++it) {
      int idx = it * 256 + tid;
      int dd2 = idx & 63, e = idx >> 6;
      float s = kvtp[e * DD + dd2];
#pragma unroll
      for (int t2 = 0; t2 < TT; ++t2)
        s -= (float)kvbp[(size_t)lu[t2] * DD * DD + e * DD + dd2];
      KH[e][dd2] = (f16)s;
    }
  }
  __syncthreads();
  {
    float dpart = 0.f;
#pragma unroll
    for (int c = 0; c < 16; ++c) dpart += cq[c] * ksq[cp * 16 + c];
    dpart += __shfl_xor(dpart, 1);
    dpart += __shfl_xor(dpart, 2);
    if (cp == 0) dinv[cr] = 1.f / (dpart + 1e-6f);
  }
  f32x4 accn[4];
  {
    half8 cqh[2];
#pragma unroll
    for (int ks = 0; ks < 2; ++ks)
      cqh[ks] = *(const half8*)&VH[w * 16 + c16][ks * 32 + g * 8];
#pragma unroll
    for (int j = 0; j < 4; ++j) {
      f32x4 acc = {0.f, 0.f, 0.f, 0.f};
#pragma unroll
      for (int ks = 0; ks < 2; ++ks) {
        half8 ah = *(const half8*)&KH[j * 16 + c16][ks * 32 + g * 8];
        acc = MFMA16(ah, cqh[ks], acc);
      }
      accn[j] = acc;
    }
  }
  __syncthreads();
  float di = dinv[w * 16 + c16];
#pragma unroll
  for (int j = 0; j < 4; ++j) {
    float o0 = accn[j][0] * di;
    float o1 = accn[j][1] * di;
    float o2 = accn[j][2] * di;
    float o3 = accn[j][3] * di;
    H4 hh, ll;
    hh.h[0] = (f16)o0; ll.h[0] = (f16)((o0 - (float)hh.h[0]) * 2048.f);
    hh.h[1] = (f16)o1; ll.h[1] = (f16)((o1 - (float)hh.h[1]) * 2048.f);
    hh.h[2] = (f16)o2; ll.h[2] = (f16)((o2 - (float)hh.h[2]) * 2048.f);
    hh.h[3] = (f16)o3; ll.h[3] = (f16)((o3 - (float)hh.h[3]) * 2048.f);
    *(ull*)&PH[w * 16 + c16][j * 16 + g * 4] = hh.u;
    *(ull*)&KH[w * 16 + c16][j * 16 + g * 4] = ll.u;
  }
  f32x4 accf2[4];
#pragma unroll
  for (int j = 0; j < 4; ++j) accf2[j] = (f32x4){0.f,0.f,0.f,0.f};
#pragma unroll
  for (int ks = 0; ks < 2; ++ks) {
    half8 bolh = *(const half8*)&PH[w * 16 + c16][ks * 32 + g * 8];
    half8 boll = *(const half8*)&KH[w * 16 + c16][ks * 32 + g * 8];
#pragma unroll
    for (int j = 0; j < 4; ++j) {
      size_t pwoff = (size_t)(j * 16 + c16) * DD + ks * 32 + g * 8;
      half8 awh = *(const half8*)(plwh + pwoff);
      half8 awl = *(const half8*)(plwl + pwoff);
      acco[j]  = MFMA16(awh, bolh, acco[j]);
      accf2[j] = MFMA16(awh, boll, accf2[j]);
      accf2[j] = MFMA16(awl, bolh, accf2[j]);
    }
  }
  size_t obase = ((size_t)b * LL + (size_t)n * BLK + w * 16 + c16) * NC + h * DD;
#pragma unroll
  for (int j = 0; j < 4; ++j) {
    H4 hh;
#pragma unroll
    for (int r = 0; r < 4; ++r) {
      int e2 = j * 16 + g * 4 + r;
      hh.h[r] = (f16)(acco[j][r] + accf2[j][r] * INV2048 + plb[e2]);
    }
    *(ull*)(och + obase + j * 16 + g * 4) = hh.u;
  }
}

// ---------------- out projection: A=W_out hi/lo (global), B=och f16 (LDS) ---
__global__ __launch_bounds__(256) void out_mfma(
    const f16* __restrict__ och,
    const f16* __restrict__ wh, const f16* __restrict__ wl,
    float* __restrict__ out) {
  __shared__ f16 OH[BLK][PAD];
  int l0 = blockIdx.x * 64;
  int o0 = blockIdx.y * 64;
  int b = blockIdx.z;
  int tid = threadIdx.x;
  int w = tid >> 6, lane = tid & 63, c16 = lane & 15, g = lane >> 4;
  f32x4 acc[4], acc2[4];
#pragma unroll
  for (int j = 0; j < 4; ++j) { acc[j] = (f32x4){0.f,0.f,0.f,0.f}; acc2[j] = (f32x4){0.f,0.f,0.f,0.f}; }
  size_t wbase = (size_t)(o0 + w * 16 + c16) * NC;
  for (int c0 = 0; c0 < NC; c0 += 64) {
    __syncthreads();
#pragma unroll
    for (int it = 0; it < 2; ++it) {
      int idx = it * 256 + tid; int pos = idx >> 3, dp8 = idx & 7;
      size_t gsrc = ((size_t)b * LL + l0 + pos) * NC + c0 + dp8 * 8;
      *(uint4v*)&OH[pos][dp8 * 8] = *(const uint4v*)(och + gsrc);
    }
    __syncthreads();
#pragma unroll
    for (int ks = 0; ks < 2; ++ks) {
      half8 awh = *(const half8*)(wh + wbase + c0 + ks * 32 + g * 8);
      half8 awl = *(const half8*)(wl + wbase + c0 + ks * 32 + g * 8);
#pragma unroll
      for (int j = 0; j < 4; ++j) {
        half8 bh = *(const half8*)&OH[j * 16 + c16][ks * 32 + g * 8];
        acc[j]  = MFMA16(awh, bh, acc[j]);
        acc2[j] = MFMA16(awl, bh, acc2[j]);
      }
    }
  }
#pragma unroll
  for (int j = 0; j < 4; ++j)
#pragma unroll
    for (int r = 0; r < 4; ++r)
      out[((size_t)b * NC + o0 + w * 16 + g * 4 + r) * LL + l0 + j * 16 + c16] =
          acc[j][r] + acc2[j][r] * INV2048;
}

extern "C" void kernel_launch(void* const* d_in, const int* in_sizes, int n_in,
                              void* d_out, int out_size, void* d_ws, size_t ws_size,
                              hipStream_t stream) {
  (void)in_sizes; (void)n_in; (void)out_size; (void)ws_size;
  const float* x = (const float*)d_in[0];
  const float* qkv_w = (const float*)d_in[1];
  const float* out_w = (const float*)d_in[2];
  const float* plw = (const float*)d_in[3];
  const float* plb = (const float*)d_in[4];
  float* out = (float*)d_out;
  const size_t E = (size_t)NB * NHH * LL * DD;  // 8388608
  f16* fb = (f16*)d_ws;
  f16* qh = fb;
  f16* kh = qh + E;
  f16* vT = kh + E;
  f16* xTh = vT + E;
  // och aliases xTh (xTh consumed by q/kv_mfma before attn writes och)
  f16* och = xTh;
  f16* kvbT = xTh + E;
  float* fbase = (float*)(kvbT + E);
  float* ksum = fbase;
  float* kvtot = ksum + (size_t)NB * NHH * NKB * DD;
  float* kstot = kvtot + (size_t)NB * NHH * DD * DD;
  float* xb = kstot + (size_t)NB * NHH * DD;
  float* qb = xb + (size_t)NB * NC * NQ;
  float* kb = qb + (size_t)NB * NHH * NQ * DD;
  int* lut = (int*)(kb + (size_t)NB * NHH * NQ * DD);
  f16* wqh = (f16*)(lut + (size_t)NB * NHH * NQ * TT);
  f16* woh = wqh + (size_t)3 * NC * NC;
  f16* wol = woh + (size_t)NC * NC;
  f16* plwh = wol + (size_t)NC * NC;
  f16* plwl = plwh + (size_t)DD * DD;

  xsplit_kernel<<<dim3(LL / 64, NC / 64, NB), 256, 0, stream>>>(x, xTh, xb);
  qbkb_kernel<<<NB * NQ * NHH, 128, 0, stream>>>(qkv_w, xb, qb, kb);
  topk_kernel<<<NB * NHH * NQ, 64, 0, stream>>>(qb, kb, lut);
  wsplit_kernel<<<260, 256, 0, stream>>>(qkv_w, out_w, plw, wqh, woh, wol, plwh, plwl);
  q_mfma<<<LL / 64 * NHH * NB, 256, 0, stream>>>(xTh, wqh, qh);
  kv_mfma<<<LL / 64 * NHH * NB, 256, 0, stream>>>(xTh, wqh, kh, vT, kvbT, ksum);
  totals_kernel<<<NB * NHH * 16, 256, 0, stream>>>(kvbT, ksum, kvtot, kstot);
  attn_mfma<<<NB * NHH * NQ, 256, 0, stream>>>(qh, kh, vT, kvbT, ksum,
                                               kvtot, kstot, lut, plwh, plwl, plb,
                                               och);
  out_mfma<<<dim3(LL / 64, NC / 64, NB), 256, 0, stream>>>(och, woh, wol, out);
}

// Round 19
// 177.201 us; speedup vs baseline: 1.0880x; 1.0664x over previous
//
#include <hip/hip_runtime.h>
#include <hip/hip_bf16.h>
#include <cmath>

#define NB 8
#define NC 256
#define NHH 4
#define DD 64
#define LL 4096
#define NQ 64
#define NKB 64
#define BLK 64
#define TT 6
#define PAD 72  // f16 row stride (144B = 9*16B): 16B-aligned b128 ops

typedef _Float16 f16;
typedef _Float16 half8 __attribute__((ext_vector_type(8)));
typedef float f32x4 __attribute__((ext_vector_type(4)));
typedef unsigned int uint4v __attribute__((ext_vector_type(4)));
typedef unsigned long long ull;

#define INV2048 4.8828125e-4f

union H4 { f16 h[4]; ull u; };
union H2 { f16 h[2]; unsigned int u; };

#define MFMA16(A, B, C) __builtin_amdgcn_mfma_f32_16x16x32_f16(A, B, C, 0, 0, 0)

// ---------------- qb/kb: project block means (exact f32 topk path) ----------
__global__ void qbkb_kernel(const float* __restrict__ w, const float* __restrict__ xb,
                            float* __restrict__ qb, float* __restrict__ kb) {
  int id = blockIdx.x;
  int h = id % NHH; id /= NHH;
  int n = id % NQ;  int b = id / NQ;
  int t = threadIdx.x;
  int d = t & 63;
  int part = t >> 6;
  const float* wrow = w + (size_t)(part * NC + h * DD + d) * NC;
  const float* xcol = xb + (size_t)b * NC * NQ + n;
  float acc = 0.f;
#pragma unroll 4
  for (int c = 0; c < NC; ++c) acc += wrow[c] * xcol[(size_t)c * NQ];
  float* dst = (part == 0) ? qb : kb;
  dst[(((size_t)b * NHH + h) * NQ + n) * DD + d] = acc;
}

// ---------------- topk ----------------
__global__ void topk_kernel(const float* __restrict__ qb, const float* __restrict__ kb,
                            int* __restrict__ lut) {
  __shared__ float kbs[NKB][DD + 1];
  int id = blockIdx.x;
  int n = id % NQ;
  int bh = id / NQ;
  int m = threadIdx.x;
  const float* kbp = kb + (size_t)bh * NKB * DD;
  for (int i = threadIdx.x; i < NKB * DD; i += 64) kbs[i >> 6][i & 63] = kbp[i];
  __syncthreads();
  const float* qrow = qb + ((size_t)bh * NQ + n) * DD;
  float s = 0.f;
#pragma unroll 8
  for (int d2 = 0; d2 < DD; ++d2) s += qrow[d2] * kbs[m][d2];
  for (int t = 0; t < TT; ++t) {
    float v = s; int i = m;
#pragma unroll
    for (int off = 1; off < 64; off <<= 1) {
      float ov = __shfl_xor(v, off);
      int oi = __shfl_xor(i, off);
      if (ov > v || (ov == v && oi < i)) { v = ov; i = oi; }
    }
    if (m == 0) lut[(size_t)id * TT + t] = i;
    if (m == i) s = -INFINITY;
  }
}

// ---------------- merged weight split ----------------
__global__ void wsplit_kernel(const float* __restrict__ wq, const float* __restrict__ wo,
                              const float* __restrict__ plw,
                              f16* __restrict__ wqh,
                              f16* __restrict__ woh, f16* __restrict__ wol,
                              f16* __restrict__ plwh, f16* __restrict__ plwl) {
  int blk = blockIdx.x;
  if (blk < 192) {
    int i = (blk * 256 + threadIdx.x) * 4;
    float4 v = *(const float4*)(wq + i);
    H4 hh;
    hh.h[0] = (f16)v.x; hh.h[1] = (f16)v.y; hh.h[2] = (f16)v.z; hh.h[3] = (f16)v.w;
    *(ull*)(wqh + i) = hh.u;
    return;
  }
  const float* src; f16* dh; f16* dl; int n;
  if (blk < 256) { src = wo;  dh = woh;  dl = wol;  n = NC * NC; blk -= 192; }
  else           { src = plw; dh = plwh; dl = plwl; n = DD * DD; blk -= 256; }
  int i = (blk * 256 + threadIdx.x) * 4;
  if (i >= n) return;
  float4 v = *(const float4*)(src + i);
  H4 hh, ll;
  hh.h[0] = (f16)v.x; ll.h[0] = (f16)((v.x - (float)hh.h[0]) * 2048.f);
  hh.h[1] = (f16)v.y; ll.h[1] = (f16)((v.y - (float)hh.h[1]) * 2048.f);
  hh.h[2] = (f16)v.z; ll.h[2] = (f16)((v.z - (float)hh.h[2]) * 2048.f);
  hh.h[3] = (f16)v.w; ll.h[3] = (f16)((v.w - (float)hh.h[3]) * 2048.f);
  *(ull*)(dh + i) = hh.u;
  *(ull*)(dl + i) = ll.u;
}

// ---------------- x transpose + f16 + fused block means ----------------
__global__ __launch_bounds__(256) void xsplit_kernel(const float* __restrict__ x,
                                                     f16* __restrict__ xh,
                                                     float* __restrict__ xb) {
  __shared__ float T[64][65];
  int l0 = blockIdx.x * 64, c0 = blockIdx.y * 64, b = blockIdx.z;
  int tid = threadIdx.x;
  for (int it = 0; it < 16; ++it) {
    int idx = it * 256 + tid; int c = idx >> 6, l = idx & 63;
    T[c][l] = x[((size_t)b * NC + c0 + c) * LL + l0 + l];
  }
  __syncthreads();
  {  // fused xb: 4 lanes per row, 16-elem partials + 2 shfls
    int c = tid >> 2, qq = tid & 3;
    float s = 0.f;
#pragma unroll
    for (int l = 0; l < 16; ++l) s += T[c][qq * 16 + l];
    s += __shfl_xor(s, 1);
    s += __shfl_xor(s, 2);
    if (qq == 0) xb[((size_t)b * NC + c0 + c) * NQ + blockIdx.x] = s * (1.f / 64.f);
  }
  for (int it = 0; it < 4; ++it) {
    int idx = it * 256 + tid; int l = idx >> 4, cq = idx & 15;
    H4 hh;
    hh.h[0] = (f16)T[cq * 4 + 0][l];
    hh.h[1] = (f16)T[cq * 4 + 1][l];
    hh.h[2] = (f16)T[cq * 4 + 2][l];
    hh.h[3] = (f16)T[cq * 4 + 3][l];
    *(ull*)(xh + ((size_t)b * LL + l0 + l) * NC + c0 + cq * 4) = hh.u;
  }
}

// ---------------- q+k+v GEMM with FUSED kvb (tile == key block) -------------
// One XH staging pass feeds three weight rows; q written from registers,
// then k/v restaged in LDS for vT emit + c_k softmax + ksum + kvbT.
__global__ __launch_bounds__(256) void qkv_fused(
    const f16* __restrict__ xh,
    const f16* __restrict__ wh,
    f16* __restrict__ qh,
    f16* __restrict__ kh, f16* __restrict__ vT,
    f16* __restrict__ kvbT, float* __restrict__ ksum) {
  __shared__ f16 XH[BLK][PAD];   // GEMM staging -> ck tile [l][d]
  __shared__ f16 VS[BLK][PAD];   // v tile [l][e]
  int L = blockIdx.x;
  int b = L & 7;
  int t = L >> 3;           // 0..255
  int l0 = (t >> 2) * 64;
  int h = t & 3;
  int m = l0 >> 6;          // key block index
  int tid = threadIdx.x;
  int w = tid >> 6, lane = tid & 63, c16 = lane & 15, g = lane >> 4;
  f32x4 accq[4], acck[4], accv[4];
#pragma unroll
  for (int j = 0; j < 4; ++j) {
    accq[j] = (f32x4){0.f,0.f,0.f,0.f};
    acck[j] = (f32x4){0.f,0.f,0.f,0.f};
    accv[j] = (f32x4){0.f,0.f,0.f,0.f};
  }
  size_t wqbase = (size_t)(h * DD + w * 16 + c16) * NC;
  size_t wkbase = (size_t)(NC + h * DD + w * 16 + c16) * NC;
  size_t wvbase = (size_t)(2 * NC + h * DD + w * 16 + c16) * NC;
  for (int c0 = 0; c0 < NC; c0 += 64) {
    __syncthreads();
#pragma unroll
    for (int it = 0; it < 2; ++it) {
      int idx = it * 256 + tid; int pos = idx >> 3, dp8 = idx & 7;
      size_t gsrc = ((size_t)b * LL + l0 + pos) * NC + c0 + dp8 * 8;
      *(uint4v*)&XH[pos][dp8 * 8] = *(const uint4v*)(xh + gsrc);
    }
    __syncthreads();
#pragma unroll
    for (int ks = 0; ks < 2; ++ks) {
      half8 awq = *(const half8*)(wh + wqbase + c0 + ks * 32 + g * 8);
      half8 awk = *(const half8*)(wh + wkbase + c0 + ks * 32 + g * 8);
      half8 awv = *(const half8*)(wh + wvbase + c0 + ks * 32 + g * 8);
#pragma unroll
      for (int j = 0; j < 4; ++j) {
        half8 bxh = *(const half8*)&XH[j * 16 + c16][ks * 32 + g * 8];
        accq[j] = MFMA16(awq, bxh, accq[j]);
        acck[j] = MFMA16(awk, bxh, acck[j]);
        accv[j] = MFMA16(awv, bxh, accv[j]);
      }
    }
  }
  int bh = b * NHH + h;
  // write qh + kh (registers only)
#pragma unroll
  for (int j = 0; j < 4; ++j) {
    H4 hq, hk;
#pragma unroll
    for (int r = 0; r < 4; ++r) { hq.h[r] = (f16)accq[j][r]; hk.h[r] = (f16)acck[j][r]; }
    size_t off = ((size_t)bh * LL + l0 + j * 16 + c16) * DD + w * 16 + g * 4;
    *(ull*)(qh + off) = hq.u;
    *(ull*)(kh + off) = hk.u;
  }
  __syncthreads();  // all GEMM reads of XH done
  // stage k -> XH[l][d], v -> VS[l][e]
#pragma unroll
  for (int j = 0; j < 4; ++j)
#pragma unroll
    for (int r = 0; r < 4; ++r) {
      XH[j * 16 + c16][w * 16 + g * 4 + r] = (f16)acck[j][r];
      VS[j * 16 + c16][w * 16 + g * 4 + r] = (f16)accv[j][r];
    }
  __syncthreads();
  // emit vT[bh][e][l0+..] from VS
#pragma unroll
  for (int it = 0; it < 4; ++it) {
    int idx = it * 256 + tid; int d = idx >> 4, p4 = (idx & 15) * 4;
    H4 hh;
    hh.h[0] = VS[p4 + 0][d]; hh.h[1] = VS[p4 + 1][d];
    hh.h[2] = VS[p4 + 2][d]; hh.h[3] = VS[p4 + 3][d];
    *(ull*)(vT + ((size_t)bh * DD + d) * LL + l0 + p4) = hh.u;
  }
  // c_k softmax over d, in place in XH (4 threads/row, 16 cols each)
  {
    int r = tid >> 2, p = tid & 3;
    float v[16];
    float mx = -INFINITY;
#pragma unroll
    for (int c = 0; c < 16; ++c) { v[c] = (float)XH[r][p * 16 + c]; mx = fmaxf(mx, v[c]); }
    mx = fmaxf(mx, __shfl_xor(mx, 1));
    mx = fmaxf(mx, __shfl_xor(mx, 2));
    float sum = 0.f;
#pragma unroll
    for (int c = 0; c < 16; ++c) { v[c] = __expf(v[c] - mx); sum += v[c]; }
    sum += __shfl_xor(sum, 1);
    sum += __shfl_xor(sum, 2);
    float inv = 1.0f / sum;
#pragma unroll
    for (int c = 0; c < 16; ++c) XH[r][p * 16 + c] = (f16)(v[c] * inv);
  }
  __syncthreads();
  // ksum[d] = sum_l ck[l][d]
  if (tid < DD) {
    float s = 0.f;
#pragma unroll 8
    for (int j = 0; j < BLK; ++j) s += (float)XH[j][tid];
    ksum[((size_t)bh * NKB + m) * DD + tid] = s;
  }
  // kvbT[e][d] = sum_l v[l][e] * ck[l][d]
  int tx = tid & 15, ty = tid >> 4;
  float acc[4][4] = {};
#pragma unroll 4
  for (int j = 0; j < BLK; ++j) {
    H4 va = *(H4*)&VS[j][ty * 4];
    H4 ca = *(H4*)&XH[j][tx * 4];
    float a[4], bb[4];
#pragma unroll
    for (int i = 0; i < 4; ++i) { a[i] = (float)va.h[i]; bb[i] = (float)ca.h[i]; }
#pragma unroll
    for (int i = 0; i < 4; ++i)
#pragma unroll
      for (int jj = 0; jj < 4; ++jj) acc[i][jj] += a[i] * bb[jj];
  }
  f16* dst = kvbT + ((size_t)bh * NKB + m) * DD * DD;
#pragma unroll
  for (int i = 0; i < 4; ++i) {
    H4 hh;
#pragma unroll
    for (int jj = 0; jj < 4; ++jj) hh.h[jj] = (f16)acc[i][jj];
    *(ull*)(dst + (size_t)(ty * 4 + i) * DD + tx * 4) = hh.u;
  }
}

// ---------------- totals (parallelized: 512 blocks) ----------------
__global__ void totals_kernel(const f16* __restrict__ kvbT, const float* __restrict__ ksum,
                              float* __restrict__ kvtot, float* __restrict__ kstot) {
  int bi = blockIdx.x;
  int bh = bi >> 4, s = bi & 15;
  int tid = threadIdx.x;
  int i = s * 256 + tid;
  float acc = 0.f;
  const f16* src = kvbT + (size_t)bh * NKB * DD * DD + i;
  for (int m2 = 0; m2 < NKB; ++m2) acc += (float)src[(size_t)m2 * DD * DD];
  kvtot[(size_t)bh * DD * DD + i] = acc;
  if (s == 0 && tid < DD) {
    float ss = 0.f;
    for (int m2 = 0; m2 < NKB; ++m2) ss += ksum[((size_t)bh * NKB + m2) * DD + tid];
    kstot[(size_t)bh * DD + tid] = ss;
  }
}

// ---------------- fused attention ----------------
__global__ __launch_bounds__(256) void attn_mfma(
    const f16* __restrict__ qh_g,
    const f16* __restrict__ kh_g, const f16* __restrict__ vT_g,
    const f16* __restrict__ kvbT, const float* __restrict__ ksum,
    const float* __restrict__ kvtot, const float* __restrict__ kstot,
    const int* __restrict__ lut,
    const f16* __restrict__ plwh, const f16* __restrict__ plwl,
    const float* __restrict__ plb,
    f16* __restrict__ och) {
  __shared__ f16 KH[BLK][PAD], VH[BLK][PAD], PH[BLK][PAD];
  __shared__ float ksq[DD], dinv[BLK];
  int L = blockIdx.x;
  int rest = L >> 3;
  int bh = (L & 7) * 4 + (rest >> 6);  // xcd-pinned, bh sequential per xcd
  int n = rest & 63;
  int id = bh * NQ + n;
  int b = bh >> 2, h = bh & 3;
  int tid = threadIdx.x;
  int w = tid >> 6, lane = tid & 63, c16 = lane & 15, g = lane >> 4;
  int lu[TT];
#pragma unroll
  for (int t = 0; t < TT; ++t) lu[t] = lut[(size_t)id * TT + t];
  size_t qbase = ((size_t)bh * LL + (size_t)n * BLK + w * 16 + c16) * DD;
  half8 bqh[2];
#pragma unroll
  for (int ks = 0; ks < 2; ++ks) bqh[ks] = *(const half8*)(qh_g + qbase + ks * 32 + g * 8);
  f32x4 acco[4];
#pragma unroll
  for (int j = 0; j < 4; ++j) acco[j] = (f32x4){0.f,0.f,0.f,0.f};
  float l_run = 0.f;
  // async stage registers (T14): prefetch tile 0
  uint4v kreg[2], vreg[2];
  {
    int mb = lu[0];
#pragma unroll
    for (int it = 0; it < 2; ++it) {
      int idx = it * 256 + tid; int pos = idx >> 3, dp8 = idx & 7;
      kreg[it] = *(const uint4v*)(kh_g + ((size_t)bh * LL + (size_t)mb * BLK + pos) * DD + dp8 * 8);
      vreg[it] = *(const uint4v*)(vT_g + ((size_t)bh * DD + pos) * LL + (size_t)mb * BLK + dp8 * 8);
    }
  }
  for (int t = 0; t < TT; ++t) {
    __syncthreads();  // prior tile's readers done with LDS
#pragma unroll
    for (int it = 0; it < 2; ++it) {
      int idx = it * 256 + tid; int pos = idx >> 3, dp8 = idx & 7;
      *(uint4v*)&KH[pos][dp8 * 8] = kreg[it];
      *(uint4v*)&VH[pos][dp8 * 8] = vreg[it];
    }
    __syncthreads();
    if (t + 1 < TT) {  // issue next tile's loads; latency hides under compute
      int mb = lu[t + 1];
#pragma unroll
      for (int it = 0; it < 2; ++it) {
        int idx = it * 256 + tid; int pos = idx >> 3, dp8 = idx & 7;
        kreg[it] = *(const uint4v*)(kh_g + ((size_t)bh * LL + (size_t)mb * BLK + pos) * DD + dp8 * 8);
        vreg[it] = *(const uint4v*)(vT_g + ((size_t)bh * DD + pos) * LL + (size_t)mb * BLK + dp8 * 8);
      }
    }
    // QK^T single-f16; P = exp(s/8 - 4), no max tracking
    float rs = 0.f;
#pragma unroll
    for (int i = 0; i < 4; ++i) {
      f32x4 acc = {0.f, 0.f, 0.f, 0.f};
#pragma unroll
      for (int ks = 0; ks < 2; ++ks) {
        half8 ah = *(const half8*)&KH[i * 16 + c16][ks * 32 + g * 8];
        acc = MFMA16(ah, bqh[ks], acc);
      }
      H4 pp;
#pragma unroll
      for (int r = 0; r < 4; ++r) {
        float p = __expf(acc[r] * 0.125f - 4.f);
        rs += p;
        pp.h[r] = (f16)p;
      }
      *(ull*)&PH[w * 16 + c16][i * 16 + g * 4] = pp.u;
    }
    rs += __shfl_xor(rs, 16);
    rs += __shfl_xor(rs, 32);
    l_run += rs;
#pragma unroll
    for (int ks = 0; ks < 2; ++ks) {
      half8 pb = *(const half8*)&PH[w * 16 + c16][ks * 32 + g * 8];
#pragma unroll
      for (int j = 0; j < 4; ++j) {
        half8 vhf = *(const half8*)&VH[j * 16 + c16][ks * 32 + g * 8];
        acco[j] = MFMA16(vhf, pb, acco[j]);
      }
    }
  }
  __syncthreads();  // last tile's LDS readers done before linear-path reuse
  float linv = 1.f / l_run;
#pragma unroll
  for (int j = 0; j < 4; ++j)
#pragma unroll
    for (int r = 0; r < 4; ++r) acco[j][r] *= linv;
  // ---- linear path ----
  if (tid < DD) {
    float s = kstot[(size_t)bh * DD + tid];
#pragma unroll
    for (int t2 = 0; t2 < TT; ++t2) s -= ksum[((size_t)bh * NKB + lu[t2]) * DD + tid];
    ksq[tid] = s;
  }
  int cr = tid >> 2, cp = tid & 3;
  float cq[16];
  {
    size_t qrow = ((size_t)bh * LL + (size_t)n * BLK + cr) * DD + cp * 16;
    half8 qa = *(const half8*)(qh_g + qrow), qa2 = *(const half8*)(qh_g + qrow + 8);
#pragma unroll
    for (int c = 0; c < 8; ++c) {
      cq[c] = (float)qa[c];
      cq[8 + c] = (float)qa2[c];
    }
    float mx2 = -INFINITY;
#pragma unroll
    for (int c = 0; c < 16; ++c) mx2 = fmaxf(mx2, cq[c]);
    mx2 = fmaxf(mx2, __shfl_xor(mx2, 1));
    mx2 = fmaxf(mx2, __shfl_xor(mx2, 2));
    float sum = 0.f;
#pragma unroll
    for (int c = 0; c < 16; ++c) { cq[c] = __expf(cq[c] - mx2); sum += cq[c]; }
    sum += __shfl_xor(sum, 1);
    sum += __shfl_xor(sum, 2);
    float inv = 1.f / sum;
#pragma unroll
    for (int c = 0; c < 16; ++c) cq[c] *= inv;
  }
#pragma unroll
  for (int c = 0; c < 8; ++c) {
    H2 hh;
    hh.h[0] = (f16)cq[2 * c];
    hh.h[1] = (f16)cq[2 * c + 1];
    *(unsigned int*)&VH[cr][cp * 16 + 2 * c] = hh.u;
  }
  {
    // kvq^T gather: kvbT[m][e][dd] f16, lane = dd -> lane-contiguous reads
    const float* kvtp = kvtot + (size_t)bh * DD * DD;
    const f16* kvbp = kvbT + (size_t)bh * NKB * DD * DD;
    for (int it = 0; it < 16; ++it) {
      int idx = it * 256 + tid;
      int dd2 = idx & 63, e = idx >> 6;
      float s = kvtp[e * DD + dd2];
#pragma unroll
      for (int t2 = 0; t2 < TT; ++t2)
        s -= (float)kvbp[(size_t)lu[t2] * DD * DD + e * DD + dd2];
      KH[e][dd2] = (f16)s;
    }
  }
  __syncthreads();
  {
    float dpart = 0.f;
#pragma unroll
    for (int c = 0; c < 16; ++c) dpart += cq[c] * ksq[cp * 16 + c];
    dpart += __shfl_xor(dpart, 1);
    dpart += __shfl_xor(dpart, 2);
    if (cp == 0) dinv[cr] = 1.f / (dpart + 1e-6f);
  }
  f32x4 accn[4];
  {
    half8 cqh[2];
#pragma unroll
    for (int ks = 0; ks < 2; ++ks)
      cqh[ks] = *(const half8*)&VH[w * 16 + c16][ks * 32 + g * 8];
#pragma unroll
    for (int j = 0; j < 4; ++j) {
      f32x4 acc = {0.f, 0.f, 0.f, 0.f};
#pragma unroll
      for (int ks = 0; ks < 2; ++ks) {
        half8 ah = *(const half8*)&KH[j * 16 + c16][ks * 32 + g * 8];
        acc = MFMA16(ah, cqh[ks], acc);
      }
      accn[j] = acc;
    }
  }
  __syncthreads();
  float di = dinv[w * 16 + c16];
#pragma unroll
  for (int j = 0; j < 4; ++j) {
    float o0 = accn[j][0] * di;
    float o1 = accn[j][1] * di;
    float o2 = accn[j][2] * di;
    float o3 = accn[j][3] * di;
    H4 hh, ll;
    hh.h[0] = (f16)o0; ll.h[0] = (f16)((o0 - (float)hh.h[0]) * 2048.f);
    hh.h[1] = (f16)o1; ll.h[1] = (f16)((o1 - (float)hh.h[1]) * 2048.f);
    hh.h[2] = (f16)o2; ll.h[2] = (f16)((o2 - (float)hh.h[2]) * 2048.f);
    hh.h[3] = (f16)o3; ll.h[3] = (f16)((o3 - (float)hh.h[3]) * 2048.f);
    *(ull*)&PH[w * 16 + c16][j * 16 + g * 4] = hh.u;
    *(ull*)&KH[w * 16 + c16][j * 16 + g * 4] = ll.u;
  }
  f32x4 accf2[4];
#pragma unroll
  for (int j = 0; j < 4; ++j) accf2[j] = (f32x4){0.f,0.f,0.f,0.f};
#pragma unroll
  for (int ks = 0; ks < 2; ++ks) {
    half8 bolh = *(const half8*)&PH[w * 16 + c16][ks * 32 + g * 8];
    half8 boll = *(const half8*)&KH[w * 16 + c16][ks * 32 + g * 8];
#pragma unroll
    for (int j = 0; j < 4; ++j) {
      size_t pwoff = (size_t)(j * 16 + c16) * DD + ks * 32 + g * 8;
      half8 awh = *(const half8*)(plwh + pwoff);
      half8 awl = *(const half8*)(plwl + pwoff);
      acco[j]  = MFMA16(awh, bolh, acco[j]);
      accf2[j] = MFMA16(awh, boll, accf2[j]);
      accf2[j] = MFMA16(awl, bolh, accf2[j]);
    }
  }
  size_t obase = ((size_t)b * LL + (size_t)n * BLK + w * 16 + c16) * NC + h * DD;
#pragma unroll
  for (int j = 0; j < 4; ++j) {
    H4 hh;
#pragma unroll
    for (int r = 0; r < 4; ++r) {
      int e2 = j * 16 + g * 4 + r;
      hh.h[r] = (f16)(acco[j][r] + accf2[j][r] * INV2048 + plb[e2]);
    }
    *(ull*)(och + obase + j * 16 + g * 4) = hh.u;
  }
}

// ---------------- out projection: A=W_out hi/lo (global), B=och f16 (LDS) ---
__global__ __launch_bounds__(256) void out_mfma(
    const f16* __restrict__ och,
    const f16* __restrict__ wh, const f16* __restrict__ wl,
    float* __restrict__ out) {
  __shared__ f16 OH[BLK][PAD];
  int l0 = blockIdx.x * 64;
  int o0 = blockIdx.y * 64;
  int b = blockIdx.z;
  int tid = threadIdx.x;
  int w = tid >> 6, lane = tid & 63, c16 = lane & 15, g = lane >> 4;
  f32x4 acc[4], acc2[4];
#pragma unroll
  for (int j = 0; j < 4; ++j) { acc[j] = (f32x4){0.f,0.f,0.f,0.f}; acc2[j] = (f32x4){0.f,0.f,0.f,0.f}; }
  size_t wbase = (size_t)(o0 + w * 16 + c16) * NC;
  for (int c0 = 0; c0 < NC; c0 += 64) {
    __syncthreads();
#pragma unroll
    for (int it = 0; it < 2; ++it) {
      int idx = it * 256 + tid; int pos = idx >> 3, dp8 = idx & 7;
      size_t gsrc = ((size_t)b * LL + l0 + pos) * NC + c0 + dp8 * 8;
      *(uint4v*)&OH[pos][dp8 * 8] = *(const uint4v*)(och + gsrc);
    }
    __syncthreads();
#pragma unroll
    for (int ks = 0; ks < 2; ++ks) {
      half8 awh = *(const half8*)(wh + wbase + c0 + ks * 32 + g * 8);
      half8 awl = *(const half8*)(wl + wbase + c0 + ks * 32 + g * 8);
#pragma unroll
      for (int j = 0; j < 4; ++j) {
        half8 bh = *(const half8*)&OH[j * 16 + c16][ks * 32 + g * 8];
        acc[j]  = MFMA16(awh, bh, acc[j]);
        acc2[j] = MFMA16(awl, bh, acc2[j]);
      }
    }
  }
#pragma unroll
  for (int j = 0; j < 4; ++j)
#pragma unroll
    for (int r = 0; r < 4; ++r)
      out[((size_t)b * NC + o0 + w * 16 + g * 4 + r) * LL + l0 + j * 16 + c16] =
          acc[j][r] + acc2[j][r] * INV2048;
}

extern "C" void kernel_launch(void* const* d_in, const int* in_sizes, int n_in,
                              void* d_out, int out_size, void* d_ws, size_t ws_size,
                              hipStream_t stream) {
  (void)in_sizes; (void)n_in; (void)out_size; (void)ws_size;
  const float* x = (const float*)d_in[0];
  const float* qkv_w = (const float*)d_in[1];
  const float* out_w = (const float*)d_in[2];
  const float* plw = (const float*)d_in[3];
  const float* plb = (const float*)d_in[4];
  float* out = (float*)d_out;
  const size_t E = (size_t)NB * NHH * LL * DD;  // 8388608
  f16* fb = (f16*)d_ws;
  f16* qh = fb;
  f16* kh = qh + E;
  f16* vT = kh + E;
  f16* xTh = vT + E;
  // och aliases xTh (xTh consumed by qkv_fused before attn writes och)
  f16* och = xTh;
  f16* kvbT = xTh + E;
  float* fbase = (float*)(kvbT + E);
  float* ksum = fbase;
  float* kvtot = ksum + (size_t)NB * NHH * NKB * DD;
  float* kstot = kvtot + (size_t)NB * NHH * DD * DD;
  float* xb = kstot + (size_t)NB * NHH * DD;
  float* qb = xb + (size_t)NB * NC * NQ;
  float* kb = qb + (size_t)NB * NHH * NQ * DD;
  int* lut = (int*)(kb + (size_t)NB * NHH * NQ * DD);
  f16* wqh = (f16*)(lut + (size_t)NB * NHH * NQ * TT);
  f16* woh = wqh + (size_t)3 * NC * NC;
  f16* wol = woh + (size_t)NC * NC;
  f16* plwh = wol + (size_t)NC * NC;
  f16* plwl = plwh + (size_t)DD * DD;

  xsplit_kernel<<<dim3(LL / 64, NC / 64, NB), 256, 0, stream>>>(x, xTh, xb);
  qbkb_kernel<<<NB * NQ * NHH, 128, 0, stream>>>(qkv_w, xb, qb, kb);
  topk_kernel<<<NB * NHH * NQ, 64, 0, stream>>>(qb, kb, lut);
  wsplit_kernel<<<260, 256, 0, stream>>>(qkv_w, out_w, plw, wqh, woh, wol, plwh, plwl);
  qkv_fused<<<LL / 64 * NHH * NB, 256, 0, stream>>>(xTh, wqh, qh, kh, vT, kvbT, ksum);
  totals_kernel<<<NB * NHH * 16, 256, 0, stream>>>(kvbT, ksum, kvtot, kstot);
  attn_mfma<<<NB * NHH * NQ, 256, 0, stream>>>(qh, kh, vT, kvbT, ksum,
                                               kvtot, kstot, lut, plwh, plwl, plb,
                                               och);
  out_mfma<<<dim3(LL / 64, NC / 64, NB), 256, 0, stream>>>(och, woh, wol, out);
}